// Round 1
// baseline (1988.904 us; speedup 1.0000x reference)
//
#include <hip/hip_runtime.h>

// Problem constants (fixed by the reference)
#define H_DIM    512
#define NUM_BASES 128
#define SUBMAT   4

// ---------------------------------------------------------------------------
// Kernel 1: out[M][512] = emb[M][512] @ W[512][512] + bias[512]
// fp32 tiled GEMM: BM=BN=64, BK=32, 256 threads, 4x4 accumulators/thread.
// A tile stored transposed in LDS with +1 padding (scalar broadcast reads,
// conflict-free); B tile read as float4 (2-way aliasing = free on CDNA4).
// ---------------------------------------------------------------------------
__global__ __launch_bounds__(256) void selfloop_gemm(
    const float* __restrict__ A,      // emb [M][512]
    const float* __restrict__ B,      // loop_weight [512][512]
    const float* __restrict__ bias,   // [512]
    float* __restrict__ C,            // out [M][512]
    int M) {
  __shared__ float As[32][65];   // As[k][m], padded
  __shared__ float Bs[32][64];   // Bs[k][n]

  const int tid = threadIdx.x;
  const int row0 = blockIdx.x * 64;
  const int col0 = blockIdx.y * 64;
  const int tx = tid & 15;       // n-tile position (4 cols each)
  const int ty = tid >> 4;       // m-tile position (4 rows each)

  float acc[4][4] = {};

  for (int k0 = 0; k0 < H_DIM; k0 += 32) {
    // --- stage A tile (64 rows x 32 k), transposed into As[k][m] ---
#pragma unroll
    for (int q = 0; q < 2; ++q) {
      const int f = tid + q * 256;        // 0..511
      const int kk = (f & 7) * 4;         // 0,4,..,28
      const int r = f >> 3;               // 0..63
      const int grow = row0 + r;
      float4 v = make_float4(0.f, 0.f, 0.f, 0.f);
      if (grow < M)
        v = *(const float4*)(A + (size_t)grow * H_DIM + k0 + kk);
      As[kk + 0][r] = v.x;
      As[kk + 1][r] = v.y;
      As[kk + 2][r] = v.z;
      As[kk + 3][r] = v.w;
    }
    // --- stage B tile (32 k x 64 n) ---
#pragma unroll
    for (int q = 0; q < 2; ++q) {
      const int f = tid + q * 256;        // 0..511
      const int nn = (f & 15) * 4;        // 0..60
      const int kk = f >> 4;              // 0..31
      *(float4*)(&Bs[kk][nn]) =
          *(const float4*)(B + (size_t)(k0 + kk) * H_DIM + col0 + nn);
    }
    __syncthreads();

#pragma unroll
    for (int kk = 0; kk < 32; ++kk) {
      float a[4];
#pragma unroll
      for (int i = 0; i < 4; ++i) a[i] = As[kk][ty * 4 + i];
      const float4 bv = *(const float4*)(&Bs[kk][tx * 4]);
      const float b[4] = {bv.x, bv.y, bv.z, bv.w};
#pragma unroll
      for (int i = 0; i < 4; ++i)
#pragma unroll
        for (int j = 0; j < 4; ++j)
          acc[i][j] = fmaf(a[i], b[j], acc[i][j]);
    }
    __syncthreads();
  }

  // --- epilogue: add bias, store ---
  const float4 bz = *(const float4*)(bias + col0 + tx * 4);
#pragma unroll
  for (int i = 0; i < 4; ++i) {
    const int grow = row0 + ty * 4 + i;
    if (grow < M) {
      float4 o;
      o.x = acc[i][0] + bz.x;
      o.y = acc[i][1] + bz.y;
      o.z = acc[i][2] + bz.z;
      o.w = acc[i][3] + bz.w;
      *(float4*)(C + (size_t)grow * H_DIM + col0 + tx * 4) = o;
    }
  }
}

// ---------------------------------------------------------------------------
// Kernel 2: per-edge block-diagonal message + atomic scatter-add into out.
// msg[e, 4b+o] = norm[e] * sum_i h_src[e,4b+i] * weight[etype[e], b, i, o]
// 128 threads per edge (one per base), 2 edges per 256-thread block.
// ---------------------------------------------------------------------------
__global__ __launch_bounds__(256) void edge_message(
    const int* __restrict__ src,
    const int* __restrict__ dst,
    const int* __restrict__ etypes,
    const float* __restrict__ norm,
    const float* __restrict__ emb,     // h0 == emb (node_ids is arange)
    const float* __restrict__ W,       // [2*rels][128][4][4]
    float* __restrict__ out,
    int nE) {
  const int b = threadIdx.x & 127;          // base index 0..127
  const int e = blockIdx.x * 2 + (threadIdx.x >> 7);
  if (e >= nE) return;

  const int s = src[e];
  const int d = dst[e];
  const int r = etypes[e];
  const float nrm = norm[e];

  const float4 h = *(const float4*)(emb + (size_t)s * H_DIM + b * 4);
  const float4* w = (const float4*)(W + ((size_t)r * NUM_BASES + b) * 16);
  const float4 w0 = w[0];   // weight[r][b][0][0..3]
  const float4 w1 = w[1];
  const float4 w2 = w[2];
  const float4 w3 = w[3];

  const float m0 = h.x * w0.x + h.y * w1.x + h.z * w2.x + h.w * w3.x;
  const float m1 = h.x * w0.y + h.y * w1.y + h.z * w2.y + h.w * w3.y;
  const float m2 = h.x * w0.z + h.y * w1.z + h.z * w2.z + h.w * w3.z;
  const float m3 = h.x * w0.w + h.y * w1.w + h.z * w2.w + h.w * w3.w;

  float* op = out + (size_t)d * H_DIM + b * 4;
  atomicAdd(op + 0, m0 * nrm);
  atomicAdd(op + 1, m1 * nrm);
  atomicAdd(op + 2, m2 * nrm);
  atomicAdd(op + 3, m3 * nrm);
}

// ---------------------------------------------------------------------------
// Inputs (setup_inputs order):
//  0 node_ids [100000]  (arange -> identity gather, unused)
//  1 src      [E]
//  2 dst      [E]
//  3 etypes   [E]
//  4 norm     [E]
//  5 emb      [N*512]
//  6 weight   [200*128*4*4]
//  7 loop_weight [512*512]
//  8 bias     [512]
// ---------------------------------------------------------------------------
extern "C" void kernel_launch(void* const* d_in, const int* in_sizes, int n_in,
                              void* d_out, int out_size, void* d_ws, size_t ws_size,
                              hipStream_t stream) {
  const int* src = (const int*)d_in[1];
  const int* dst = (const int*)d_in[2];
  const int* etypes = (const int*)d_in[3];
  const float* norm = (const float*)d_in[4];
  const float* emb = (const float*)d_in[5];
  const float* weight = (const float*)d_in[6];
  const float* loop_weight = (const float*)d_in[7];
  const float* bias = (const float*)d_in[8];
  float* out = (float*)d_out;

  const int nE = in_sizes[1];
  const int M = in_sizes[5] / H_DIM;

  // 1) out = emb @ loop_weight + bias   (initializes every element of out)
  dim3 ggrid((M + 63) / 64, H_DIM / 64);
  selfloop_gemm<<<ggrid, 256, 0, stream>>>(emb, loop_weight, bias, out, M);

  // 2) out += scatter-add of edge messages (same stream -> ordered)
  edge_message<<<(nE + 1) / 2, 256, 0, stream>>>(src, dst, etypes, norm, emb,
                                                 weight, out, nE);
}

// Round 2
// 876.818 us; speedup vs baseline: 2.2683x; 2.2683x over previous
//
#include <hip/hip_runtime.h>

#define H_DIM    512
#define NUM_BASES 128

typedef __attribute__((ext_vector_type(4))) float f32x4;
typedef __attribute__((ext_vector_type(8))) short bf16x8;

__device__ __forceinline__ short f32_bf16(float f) {
  union { float f; unsigned u; } x; x.f = f;
  unsigned r = x.u + 0x7FFF + ((x.u >> 16) & 1);   // RNE
  return (short)(r >> 16);
}
__device__ __forceinline__ float bf16_f32(short s) {
  union { unsigned u; float f; } x; x.u = ((unsigned)(unsigned short)s) << 16;
  return x.f;
}

// ---------------------------------------------------------------------------
// B-prep: loop_weight [K=512][N=512] fp32  ->  Bt_hi/Bt_lo [N][K] bf16
// (transposed so GEMM B-fragments are K-contiguous; hi/lo split-bf16)
// ---------------------------------------------------------------------------
__global__ __launch_bounds__(256) void bprep(const float* __restrict__ B,
                                             short* __restrict__ Bt_hi,
                                             short* __restrict__ Bt_lo) {
  __shared__ float T[32][33];
  const int k0 = blockIdx.x * 32, n0 = blockIdx.y * 32;
  const int tid = threadIdx.x;
#pragma unroll
  for (int q = 0; q < 4; ++q) {
    int idx = tid + q * 256;
    int kk = idx >> 5, nn = idx & 31;
    T[kk][nn] = B[(k0 + kk) * H_DIM + n0 + nn];
  }
  __syncthreads();
#pragma unroll
  for (int q = 0; q < 4; ++q) {
    int idx = tid + q * 256;
    int nn = idx >> 5, kk = idx & 31;
    float v = T[kk][nn];
    short hi = f32_bf16(v);
    short lo = f32_bf16(v - bf16_f32(hi));
    Bt_hi[(size_t)(n0 + nn) * H_DIM + k0 + kk] = hi;
    Bt_lo[(size_t)(n0 + nn) * H_DIM + k0 + kk] = lo;
  }
}

// ---------------------------------------------------------------------------
// MFMA GEMM: C = A @ B + bias via split-bf16 (Ah@Bh + Ah@Bl + Al@Bh).
// 128x128 tile, BK=64, 4 waves (2x2), each wave 64x64 via 4x4 16x16x32 frags.
// LDS XOR-swizzle ((row&7)<<3 in shorts) -> conflict-free ds_read_b128.
// ---------------------------------------------------------------------------
__global__ __launch_bounds__(256) void mfma_gemm(
    const float* __restrict__ A,       // emb [M][512] fp32
    const short* __restrict__ Bt_hi,   // [512(n)][512(k)] bf16
    const short* __restrict__ Bt_lo,
    const float* __restrict__ bias,
    float* __restrict__ C, int M) {
  __shared__ short sAh[8192], sAl[8192], sBh[8192], sBl[8192];  // 4 x 16KB

  const int tid = threadIdx.x;
  const int lane = tid & 63;
  const int wave = tid >> 6;
  const int col0 = blockIdx.x * 128;   // n offset (grid.x = 4, fastest -> L2 reuse of A panel)
  const int row0 = blockIdx.y * 128;   // m offset
  const int wm = (wave >> 1) * 64;
  const int wn = (wave & 1) * 64;
  const int l15 = lane & 15;
  const int l4 = lane >> 4;

  f32x4 acc[4][4] = {};

  for (int k0 = 0; k0 < H_DIM; k0 += 64) {
#pragma unroll
    for (int q = 0; q < 8; ++q) {
      const int f = tid + q * 256;       // 0..2047
      const int row = f >> 4;            // 0..127
      const int col = (f & 15) * 4;      // 0..60
      const int si = ((row << 6) + col) ^ ((row & 7) << 3);
      // A: fp32 -> hi/lo bf16 on the fly
      float4 v = make_float4(0.f, 0.f, 0.f, 0.f);
      const int grow = row0 + row;
      if (grow < M) v = *(const float4*)(A + (size_t)grow * H_DIM + k0 + col);
      short h0 = f32_bf16(v.x), h1 = f32_bf16(v.y), h2 = f32_bf16(v.z), h3 = f32_bf16(v.w);
      short e0 = f32_bf16(v.x - bf16_f32(h0)), e1 = f32_bf16(v.y - bf16_f32(h1));
      short e2 = f32_bf16(v.z - bf16_f32(h2)), e3 = f32_bf16(v.w - bf16_f32(h3));
      *(short4*)&sAh[si] = make_short4(h0, h1, h2, h3);
      *(short4*)&sAl[si] = make_short4(e0, e1, e2, e3);
      // B: already bf16 hi/lo, [n][k] layout
      *(short4*)&sBh[si] = *(const short4*)(Bt_hi + (size_t)(col0 + row) * H_DIM + k0 + col);
      *(short4*)&sBl[si] = *(const short4*)(Bt_lo + (size_t)(col0 + row) * H_DIM + k0 + col);
    }
    __syncthreads();

#pragma unroll
    for (int kk = 0; kk < 2; ++kk) {
      bf16x8 ah[4], al[4], bh[4], bl[4];
      const int cbase = kk * 32 + l4 * 8;
#pragma unroll
      for (int i = 0; i < 4; ++i) {
        const int ra = wm + 16 * i + l15;
        const int sia = ((ra << 6) + cbase) ^ ((ra & 7) << 3);
        ah[i] = *(const bf16x8*)&sAh[sia];
        al[i] = *(const bf16x8*)&sAl[sia];
        const int rb = wn + 16 * i + l15;
        const int sib = ((rb << 6) + cbase) ^ ((rb & 7) << 3);
        bh[i] = *(const bf16x8*)&sBh[sib];
        bl[i] = *(const bf16x8*)&sBl[sib];
      }
#pragma unroll
      for (int i = 0; i < 4; ++i)
#pragma unroll
        for (int j = 0; j < 4; ++j) {
          acc[i][j] = __builtin_amdgcn_mfma_f32_16x16x32_bf16(ah[i], bh[j], acc[i][j], 0, 0, 0);
          acc[i][j] = __builtin_amdgcn_mfma_f32_16x16x32_bf16(ah[i], bl[j], acc[i][j], 0, 0, 0);
          acc[i][j] = __builtin_amdgcn_mfma_f32_16x16x32_bf16(al[i], bh[j], acc[i][j], 0, 0, 0);
        }
    }
    __syncthreads();
  }

  // epilogue: bias + store (C/D layout: col = lane&15, row = (lane>>4)*4 + reg)
  float bv[4];
#pragma unroll
  for (int j = 0; j < 4; ++j) bv[j] = bias[col0 + wn + 16 * j + l15];
#pragma unroll
  for (int i = 0; i < 4; ++i) {
#pragma unroll
    for (int r = 0; r < 4; ++r) {
      const int grow = row0 + wm + 16 * i + l4 * 4 + r;
      if (grow < M) {
#pragma unroll
        for (int j = 0; j < 4; ++j)
          C[(size_t)grow * H_DIM + col0 + wn + 16 * j + l15] = acc[i][j][r] + bv[j];
      }
    }
  }
}

// ---------------------------------------------------------------------------
// Edge path: per-dst linked list (no scan), then gather-side aggregation.
// ---------------------------------------------------------------------------
__global__ void init_head(int* head, int N) {
  int i = blockIdx.x * 256 + threadIdx.x;
  if (i < N) head[i] = -1;
}

__global__ void fill_ll(const int* __restrict__ dst, int* head, int* next, int E) {
  int e = blockIdx.x * 256 + threadIdx.x;
  if (e < E) next[e] = atomicExch(&head[dst[e]], e);
}

__global__ __launch_bounds__(256) void edge_agg(
    const int* __restrict__ head, const int* __restrict__ next,
    const int* __restrict__ src, const int* __restrict__ et,
    const float* __restrict__ norm, const float* __restrict__ emb,
    const float* __restrict__ W, float* __restrict__ out, int N) {
  const int node = blockIdx.x * 2 + (threadIdx.x >> 7);
  if (node >= N) return;
  const int b = threadIdx.x & 127;
  int e = head[node];
  if (e < 0) return;                       // out already holds GEMM result
  float ax = 0.f, ay = 0.f, az = 0.f, aw = 0.f;
  while (e >= 0) {
    const int s = src[e];
    const int r = et[e];
    const float nrm = norm[e];
    const float4 h = *(const float4*)(emb + (size_t)s * H_DIM + b * 4);
    const float4* w = (const float4*)(W + ((size_t)r * NUM_BASES + b) * 16);
    const float4 w0 = w[0], w1 = w[1], w2 = w[2], w3 = w[3];
    ax += nrm * (h.x * w0.x + h.y * w1.x + h.z * w2.x + h.w * w3.x);
    ay += nrm * (h.x * w0.y + h.y * w1.y + h.z * w2.y + h.w * w3.y);
    az += nrm * (h.x * w0.z + h.y * w1.z + h.z * w2.z + h.w * w3.z);
    aw += nrm * (h.x * w0.w + h.y * w1.w + h.z * w2.w + h.w * w3.w);
    e = next[e];
  }
  float4* op = (float4*)(out + (size_t)node * H_DIM + b * 4);
  float4 cur = *op;
  cur.x += ax; cur.y += ay; cur.z += az; cur.w += aw;
  *op = cur;
}

// ---------------------------------------------------------------------------
// Fallback path (ws too small): round-0 kernels.
// ---------------------------------------------------------------------------
__global__ __launch_bounds__(256) void selfloop_gemm(
    const float* __restrict__ A, const float* __restrict__ B,
    const float* __restrict__ bias, float* __restrict__ C, int M) {
  __shared__ float As[32][65];
  __shared__ float Bs[32][64];
  const int tid = threadIdx.x;
  const int row0 = blockIdx.x * 64;
  const int col0 = blockIdx.y * 64;
  const int tx = tid & 15;
  const int ty = tid >> 4;
  float acc[4][4] = {};
  for (int k0 = 0; k0 < H_DIM; k0 += 32) {
#pragma unroll
    for (int q = 0; q < 2; ++q) {
      const int f = tid + q * 256;
      const int kk = (f & 7) * 4;
      const int r = f >> 3;
      const int grow = row0 + r;
      float4 v = make_float4(0.f, 0.f, 0.f, 0.f);
      if (grow < M) v = *(const float4*)(A + (size_t)grow * H_DIM + k0 + kk);
      As[kk + 0][r] = v.x; As[kk + 1][r] = v.y; As[kk + 2][r] = v.z; As[kk + 3][r] = v.w;
    }
#pragma unroll
    for (int q = 0; q < 2; ++q) {
      const int f = tid + q * 256;
      const int nn = (f & 15) * 4;
      const int kk = f >> 4;
      *(float4*)(&Bs[kk][nn]) = *(const float4*)(B + (size_t)(k0 + kk) * H_DIM + col0 + nn);
    }
    __syncthreads();
#pragma unroll
    for (int kk = 0; kk < 32; ++kk) {
      float a[4];
#pragma unroll
      for (int i = 0; i < 4; ++i) a[i] = As[kk][ty * 4 + i];
      const float4 bvv = *(const float4*)(&Bs[kk][tx * 4]);
      const float bb[4] = {bvv.x, bvv.y, bvv.z, bvv.w};
#pragma unroll
      for (int i = 0; i < 4; ++i)
#pragma unroll
        for (int j = 0; j < 4; ++j) acc[i][j] = fmaf(a[i], bb[j], acc[i][j]);
    }
    __syncthreads();
  }
  const float4 bz = *(const float4*)(bias + col0 + tx * 4);
#pragma unroll
  for (int i = 0; i < 4; ++i) {
    const int grow = row0 + ty * 4 + i;
    if (grow < M) {
      float4 o;
      o.x = acc[i][0] + bz.x; o.y = acc[i][1] + bz.y;
      o.z = acc[i][2] + bz.z; o.w = acc[i][3] + bz.w;
      *(float4*)(C + (size_t)grow * H_DIM + col0 + tx * 4) = o;
    }
  }
}

__global__ __launch_bounds__(256) void edge_message(
    const int* __restrict__ src, const int* __restrict__ dst,
    const int* __restrict__ etypes, const float* __restrict__ norm,
    const float* __restrict__ emb, const float* __restrict__ W,
    float* __restrict__ out, int nE) {
  const int b = threadIdx.x & 127;
  const int e = blockIdx.x * 2 + (threadIdx.x >> 7);
  if (e >= nE) return;
  const int s = src[e];
  const int d = dst[e];
  const int r = etypes[e];
  const float nrm = norm[e];
  const float4 h = *(const float4*)(emb + (size_t)s * H_DIM + b * 4);
  const float4* w = (const float4*)(W + ((size_t)r * NUM_BASES + b) * 16);
  const float4 w0 = w[0], w1 = w[1], w2 = w[2], w3 = w[3];
  const float m0 = h.x * w0.x + h.y * w1.x + h.z * w2.x + h.w * w3.x;
  const float m1 = h.x * w0.y + h.y * w1.y + h.z * w2.y + h.w * w3.y;
  const float m2 = h.x * w0.z + h.y * w1.z + h.z * w2.z + h.w * w3.z;
  const float m3 = h.x * w0.w + h.y * w1.w + h.z * w2.w + h.w * w3.w;
  float* op = out + (size_t)d * H_DIM + b * 4;
  atomicAdd(op + 0, m0 * nrm);
  atomicAdd(op + 1, m1 * nrm);
  atomicAdd(op + 2, m2 * nrm);
  atomicAdd(op + 3, m3 * nrm);
}

// ---------------------------------------------------------------------------
extern "C" void kernel_launch(void* const* d_in, const int* in_sizes, int n_in,
                              void* d_out, int out_size, void* d_ws, size_t ws_size,
                              hipStream_t stream) {
  const int* src = (const int*)d_in[1];
  const int* dst = (const int*)d_in[2];
  const int* etypes = (const int*)d_in[3];
  const float* norm = (const float*)d_in[4];
  const float* emb = (const float*)d_in[5];
  const float* weight = (const float*)d_in[6];
  const float* loop_weight = (const float*)d_in[7];
  const float* bias = (const float*)d_in[8];
  float* out = (float*)d_out;

  const int nE = in_sizes[1];
  const int M = in_sizes[5] / H_DIM;

  // ws layout: head[M] ints | next[nE] ints | Bt_hi [512*512] bf16 | Bt_lo
  const size_t bt_off = (((size_t)(M + nE) * 4) + 15) & ~(size_t)15;
  const size_t ws_needed = bt_off + 2 * (size_t)H_DIM * H_DIM * 2;

  if (ws_size >= ws_needed) {
    int* head = (int*)d_ws;
    int* next = head + M;
    short* Bt_hi = (short*)((char*)d_ws + bt_off);
    short* Bt_lo = Bt_hi + (size_t)H_DIM * H_DIM;

    dim3 bg(H_DIM / 32, H_DIM / 32);
    bprep<<<bg, 256, 0, stream>>>(loop_weight, Bt_hi, Bt_lo);
    init_head<<<(M + 255) / 256, 256, 0, stream>>>(head, M);
    fill_ll<<<(nE + 255) / 256, 256, 0, stream>>>(dst, head, next, nE);

    dim3 gg(H_DIM / 128, (M + 127) / 128);  // x = n-tile fastest (A-panel L2 reuse)
    mfma_gemm<<<gg, 256, 0, stream>>>(emb, Bt_hi, Bt_lo, bias, out, M);

    edge_agg<<<(M + 1) / 2, 256, 0, stream>>>(head, next, src, etypes, norm,
                                              emb, weight, out, M);
  } else {
    dim3 ggrid((M + 63) / 64, H_DIM / 64);
    selfloop_gemm<<<ggrid, 256, 0, stream>>>(emb, loop_weight, bias, out, M);
    edge_message<<<(nE + 1) / 2, 256, 0, stream>>>(src, dst, etypes, norm, emb,
                                                   weight, out, nE);
  }
}